// Round 4
// baseline (528.179 us; speedup 1.0000x reference)
//
#include <hip/hip_runtime.h>
#include <hip/hip_cooperative_groups.h>

namespace cg = cooperative_groups;

// Problem constants (from reference setup_inputs)
#define BB 16
#define CC 32
#define HH 256
#define WW 256
#define OHH 256
#define OWW 256
#define HW  (HH * WW)

// Work-item geometry (r2 layout — best measured):
//   transpose tile = 1 row x 64 wide -> 1024 tiles/batch
//   gather unit    = 128 pixels      -> 512 units/batch (2 lanes/pixel)
#define TBLK_HALF (8 * HH * (WW / 64))     // 8192 transpose items / 8 batches
#define GBLK_HALF (8 * (HW / 128))         // 4096 gather items / 8 batches
#define MIX_ITEMS (TBLK_HALF + GBLK_HALF)  // 12288 = 512 periods * 24

#define FUSED_BLOCKS 1024                  // 4/CU guaranteed (256thr,128VGPR,8.4KB LDS)

typedef _Float16 half8 __attribute__((ext_vector_type(8)));
typedef float float4v __attribute__((ext_vector_type(4)));

// ---------------------------------------------------------------------------
// Transpose one 64-wide row-tile of one batch: NCHW f32 -> NHWC fp16.
// ---------------------------------------------------------------------------
__device__ __forceinline__ void transpose_tile(
    const float* __restrict__ Im, _Float16* __restrict__ img,
    int b, int h, int w0, bool nt, float* lds)
{
    int t = threadIdx.x;
    const float* src = Im + ((size_t)b * CC * HH + h) * WW;
    #pragma unroll
    for (int i = 0; i < 2; ++i) {
        int idx = i * 256 + t;          // 512 covers 32c x 16 float4
        int c  = idx >> 4;
        int wq = (idx & 15) * 4;
        float4v v = __builtin_nontemporal_load(
            (const float4v*)(src + (size_t)c * HW + w0 + wq));
        lds[(wq + 0) * 33 + c] = v.x;
        lds[(wq + 1) * 33 + c] = v.y;
        lds[(wq + 2) * 33 + c] = v.z;
        lds[(wq + 3) * 33 + c] = v.w;
    }
    __syncthreads();
    int w  = t >> 2;                    // 0..63
    int c8 = (t & 3) * 8;               // {0,8,16,24}
    half8 v;
    #pragma unroll
    for (int j = 0; j < 8; ++j)
        v[j] = (_Float16)lds[w * 33 + c8 + j];
    _Float16* dstp = img + (((size_t)b * HH + h) * WW + w0 + w) * CC + c8;
    if (nt) __builtin_nontemporal_store(v, (half8*)dstp);  // don't thrash L2
    else    *(half8*)dstp = v;
    __syncthreads();                    // LDS safe for caller's next iter
}

// ---------------------------------------------------------------------------
// Bilinear gather for one 128-pixel unit of batch b: 2 threads/pixel,
// 16 channels each (r2 org — 8 independent 16B loads/thread for MLP,
// 128B-coalesced G loads). NT on G/out so streams don't evict the image.
// ---------------------------------------------------------------------------
__device__ __forceinline__ void gather_unit(
    const _Float16* __restrict__ img, const float* __restrict__ G,
    float* __restrict__ out, int b, int u)
{
    int t    = threadIdx.x;
    int hid  = t & 1;                  // channel half
    int pixb = u * 128 + (t >> 1);     // pixel within batch [0, 65536)

    const float* Gb = G + (size_t)b * 2 * HW + pixb;
    float gx = __builtin_nontemporal_load(Gb);
    float gy = __builtin_nontemporal_load(Gb + HW);

    // Reference math: replicate-pad by 1, coords shifted +1, clamp in the
    // padded frame, weights from the CLAMPED x1/y1.
    float x = gx + 1.0f;
    float y = gy + 1.0f;
    int x0 = (int)floorf(x);
    int y0 = (int)floorf(y);
    int x1 = x0 + 1;
    int y1 = y0 + 1;
    x0 = min(max(x0, 0), WW + 1);
    x1 = min(max(x1, 0), WW + 1);
    y0 = min(max(y0, 0), HH + 1);
    y1 = min(max(y1, 0), HH + 1);
    float dx = (float)x1 - x;
    float dy = (float)y1 - y;

    int xi0 = min(max(x0 - 1, 0), WW - 1);
    int xi1 = min(max(x1 - 1, 0), WW - 1);
    int yi0 = min(max(y0 - 1, 0), HH - 1);
    int yi1 = min(max(y1 - 1, 0), HH - 1);

    float wa = dy * dx;                     // (y0, x0)
    float wb = (1.0f - dy) * dx;            // (y1, x0)
    float wc = dy * (1.0f - dx);            // (y0, x1)
    float wd = (1.0f - dy) * (1.0f - dx);   // (y1, x1)

    const _Float16* base = img + (size_t)b * HW * CC + hid * 16;
    const half8* pa = (const half8*)(base + ((size_t)yi0 * WW + xi0) * CC);
    const half8* pb = (const half8*)(base + ((size_t)yi1 * WW + xi0) * CC);
    const half8* pc = (const half8*)(base + ((size_t)yi0 * WW + xi1) * CC);
    const half8* pd = (const half8*)(base + ((size_t)yi1 * WW + xi1) * CC);

    half8 a0 = pa[0], a1 = pa[1];
    half8 b0 = pb[0], b1 = pb[1];
    half8 c0 = pc[0], c1 = pc[1];
    half8 d0 = pd[0], d1 = pd[1];

    float r[16];
    #pragma unroll
    for (int j = 0; j < 8; ++j) {
        r[j]     = wa * (float)a0[j] + wb * (float)b0[j]
                 + wc * (float)c0[j] + wd * (float)d0[j];
        r[j + 8] = wa * (float)a1[j] + wb * (float)b1[j]
                 + wc * (float)c1[j] + wd * (float)d1[j];
    }

    float* outp = out + ((size_t)b * CC + hid * 16) * HW + pixb;
    #pragma unroll
    for (int j = 0; j < 16; ++j) {
        __builtin_nontemporal_store(r[j], outp + j * HW);
    }
}

// ---------------------------------------------------------------------------
// Fused persistent-block pipeline (cooperative launch):
//   Phase A: transpose batches 8..15 (img stores cached -> L2-warm)
//   Phase B: gather 8..15 || transpose 0..7 (NT img stores)
//   Phase C: gather 0..7
// grid.sync() between phases provides the producer->consumer ordering with
// device-scope visibility. 1024 blocks, stride loops; gridDim%8==0 keeps
// (i&7) == (blockIdx&7), preserving batch<->XCD L2 affinity in every phase.
// ---------------------------------------------------------------------------
__global__ __launch_bounds__(256, 4) void fused(
    const float* __restrict__ Im, _Float16* __restrict__ img,
    const float* __restrict__ G, float* __restrict__ out)
{
    __shared__ float lds[64 * 33];
    cg::grid_group grid = cg::this_grid();
    int nb = gridDim.x;

    for (int i = blockIdx.x; i < TBLK_HALF; i += nb) {          // 8 iters
        int b = 8 + (i & 7);
        int slot = i >> 3;
        transpose_tile(Im, img, b, slot >> 2, (slot & 3) * 64, false, lds);
    }
    grid.sync();

    for (int i = blockIdx.x; i < MIX_ITEMS; i += nb) {          // 12 iters
        int q = i / 24;
        int r = i - q * 24;                // uniform per block per iter
        if (r < 8) {
            gather_unit(img, G, out, 8 + r, q);
        } else {
            int xcd = r & 7;
            int ti  = q * 2 + (r >> 4);
            transpose_tile(Im, img, xcd, ti >> 2, (ti & 3) * 64, true, lds);
        }
    }
    grid.sync();

    for (int i = blockIdx.x; i < GBLK_HALF; i += nb) {          // 4 iters
        gather_unit(img, G, out, i & 7, i >> 3);
    }
}

// ---------------------------------------------------------------------------
// Non-cooperative fallback path (identical structure as separate kernels).
// ---------------------------------------------------------------------------
__global__ __launch_bounds__(256) void tpass1(
    const float* __restrict__ Im, _Float16* __restrict__ img)
{
    __shared__ float lds[64 * 33];
    int m = blockIdx.x;
    int b = 8 + (m & 7);
    int slot = m >> 3;
    transpose_tile(Im, img, b, slot >> 2, (slot & 3) * 64, false, lds);
}

__global__ __launch_bounds__(256) void mixpass(
    const float* __restrict__ Im, _Float16* __restrict__ img,
    const float* __restrict__ G, float* __restrict__ out)
{
    __shared__ float lds[64 * 33];
    int m = blockIdx.x;
    int q = m / 24;
    int r = m - q * 24;
    if (r < 8) {
        gather_unit(img, G, out, 8 + r, q);
    } else {
        int xcd = r & 7;
        int ti  = q * 2 + (r >> 4);
        transpose_tile(Im, img, xcd, ti >> 2, (ti & 3) * 64, true, lds);
    }
}

__global__ __launch_bounds__(256) void gpass3(
    const _Float16* __restrict__ img, const float* __restrict__ G,
    float* __restrict__ out)
{
    int m = blockIdx.x;
    gather_unit(img, G, out, m & 7, m >> 3);
}

// ---------------------------------------------------------------------------
// Fallback (direct kernel) in case ws is too small.
// ---------------------------------------------------------------------------
__global__ __launch_bounds__(256) void bilerp_direct(
    const float* __restrict__ Im, const float* __restrict__ G,
    float* __restrict__ out)
{
    int idx = blockIdx.x * blockDim.x + threadIdx.x;
    int ox = idx & (OWW - 1);
    int oy = (idx >> 8) & (OHH - 1);
    int b  = idx >> 16;

    const float* Gb = G + (size_t)b * 2 * HW + oy * OWW + ox;
    float x = Gb[0] + 1.0f;
    float y = Gb[HW] + 1.0f;
    int x0 = (int)floorf(x), y0 = (int)floorf(y);
    int x1 = x0 + 1, y1 = y0 + 1;
    x0 = min(max(x0, 0), WW + 1); x1 = min(max(x1, 0), WW + 1);
    y0 = min(max(y0, 0), HH + 1); y1 = min(max(y1, 0), HH + 1);
    float dx = (float)x1 - x, dy = (float)y1 - y;
    int xi0 = min(max(x0 - 1, 0), WW - 1), xi1 = min(max(x1 - 1, 0), WW - 1);
    int yi0 = min(max(y0 - 1, 0), HH - 1), yi1 = min(max(y1 - 1, 0), HH - 1);
    float wa = dy * dx, wb = (1.0f - dy) * dx;
    float wc = dy * (1.0f - dx), wd = (1.0f - dy) * (1.0f - dx);

    const float* Ibase = Im + (size_t)b * CC * HW;
    int o00 = yi0 * WW + xi0, o01 = yi0 * WW + xi1;
    int o10 = yi1 * WW + xi0, o11 = yi1 * WW + xi1;
    float* outp = out + (size_t)b * CC * HW + oy * OWW + ox;
    #pragma unroll 4
    for (int c = 0; c < CC; ++c) {
        const float* p = Ibase + c * HW;
        outp[c * HW] = wa * p[o00] + wb * p[o10] + wc * p[o01] + wd * p[o11];
    }
}

extern "C" void kernel_launch(void* const* d_in, const int* in_sizes, int n_in,
                              void* d_out, int out_size, void* d_ws, size_t ws_size,
                              hipStream_t stream) {
    const float* Im = (const float*)d_in[0];
    const float* G  = (const float*)d_in[1];
    float* out = (float*)d_out;

    const size_t needed = (size_t)BB * HW * CC * sizeof(_Float16);  // 64 MB
    int total = BB * OHH * OWW;

    if (ws_size >= needed) {
        _Float16* nhwc = (_Float16*)d_ws;
        void* args[] = { (void*)&Im, (void*)&nhwc, (void*)&G, (void*)&out };
        hipError_t e = hipLaunchCooperativeKernel(
            (const void*)fused, dim3(FUSED_BLOCKS), dim3(256), args, 0, stream);
        if (e != hipSuccess) {
            // Fall back to the verified 3-kernel pipeline (r2: 264.3 us).
            tpass1 <<<dim3(TBLK_HALF), dim3(256), 0, stream>>>(Im, nhwc);
            mixpass<<<dim3(MIX_ITEMS), dim3(256), 0, stream>>>(Im, nhwc, G, out);
            gpass3 <<<dim3(GBLK_HALF), dim3(256), 0, stream>>>(nhwc, G, out);
        }
    } else {
        bilerp_direct<<<dim3(total / 256), dim3(256), 0, stream>>>(Im, G, out);
    }
}

// Round 5
// 263.217 us; speedup vs baseline: 2.0066x; 2.0066x over previous
//
#include <hip/hip_runtime.h>

// Problem constants (from reference setup_inputs)
#define BB 16
#define CC 32
#define HH 256
#define WW 256
#define OHH 256
#define OWW 256
#define HW  (HH * WW)

// Launch geometry (r2 layout — best measured: 264.3 us):
//   transpose tile = 1 row x 64 wide  -> 256*4 = 1024 tiles/batch
//   gather unit    = 128 pixels       -> 65536/128 = 512 units/batch
#define TBLK_HALF (8 * HH * (WW / 64))   // 8192 transpose blocks per 8 batches
#define GBLK_HALF (8 * (HW / 128))       // 4096 gather blocks per 8 batches
#define MIX_BLOCKS (TBLK_HALF + GBLK_HALF)  // 12288 = 512 periods * 24

typedef _Float16 half8 __attribute__((ext_vector_type(8)));
typedef float float4v __attribute__((ext_vector_type(4)));

// ---------------------------------------------------------------------------
// Transpose one 64-wide row-tile of one batch: NCHW f32 -> NHWC fp16.
// Read phase: 2x float4 NT loads/thread (4 coalesced 256B segments per wave).
// Write phase: single half8 (16B) store per thread (256 thr x 8 half = tile).
// ---------------------------------------------------------------------------
__device__ __forceinline__ void transpose_tile(
    const float* __restrict__ Im, _Float16* __restrict__ img,
    int b, int h, int w0, bool nt, float* lds)
{
    int t = threadIdx.x;
    const float* src = Im + ((size_t)b * CC * HH + h) * WW;
    #pragma unroll
    for (int i = 0; i < 2; ++i) {
        int idx = i * 256 + t;          // 512 covers 32c x 16 float4
        int c  = idx >> 4;
        int wq = (idx & 15) * 4;
        float4v v = __builtin_nontemporal_load(
            (const float4v*)(src + (size_t)c * HW + w0 + wq));
        lds[(wq + 0) * 33 + c] = v.x;
        lds[(wq + 1) * 33 + c] = v.y;
        lds[(wq + 2) * 33 + c] = v.z;
        lds[(wq + 3) * 33 + c] = v.w;
    }
    __syncthreads();
    int w  = t >> 2;                    // 0..63
    int c8 = (t & 3) * 8;               // {0,8,16,24}
    half8 v;
    #pragma unroll
    for (int j = 0; j < 8; ++j)
        v[j] = (_Float16)lds[w * 33 + c8 + j];
    _Float16* dstp = img + (((size_t)b * HH + h) * WW + w0 + w) * CC + c8;
    if (nt) __builtin_nontemporal_store(v, (half8*)dstp);  // don't thrash L2
    else    *(half8*)dstp = v;
}

// ---------------------------------------------------------------------------
// Bilinear gather for one 128-pixel unit of batch b. Two threads per pixel
// (16 channels each): 8 independent 16B corner loads per thread (MLP),
// 128B-coalesced G loads. Output stores + G loads nontemporal so the
// streams don't evict the fp16 image from L2.
// Fabric-byte model (r4 counters): corner reads are 4 x 64B lines/pixel,
// served by L2/L3 (FETCH showed they never reach HBM). Slice total ~627MB
// through the fabric ~= 100us floor; this structure measures ~104us.
// ---------------------------------------------------------------------------
__device__ __forceinline__ void gather_unit(
    const _Float16* __restrict__ img, const float* __restrict__ G,
    float* __restrict__ out, int b, int u)
{
    int t    = threadIdx.x;
    int hid  = t & 1;                  // channel half
    int pixb = u * 128 + (t >> 1);     // pixel within batch [0, 65536)

    const float* Gb = G + (size_t)b * 2 * HW + pixb;
    float gx = __builtin_nontemporal_load(Gb);
    float gy = __builtin_nontemporal_load(Gb + HW);

    // Reference math: replicate-pad by 1, coords shifted +1, clamp in the
    // padded frame, weights from the CLAMPED x1/y1.
    float x = gx + 1.0f;
    float y = gy + 1.0f;
    int x0 = (int)floorf(x);
    int y0 = (int)floorf(y);
    int x1 = x0 + 1;
    int y1 = y0 + 1;
    x0 = min(max(x0, 0), WW + 1);
    x1 = min(max(x1, 0), WW + 1);
    y0 = min(max(y0, 0), HH + 1);
    y1 = min(max(y1, 0), HH + 1);
    float dx = (float)x1 - x;
    float dy = (float)y1 - y;

    int xi0 = min(max(x0 - 1, 0), WW - 1);
    int xi1 = min(max(x1 - 1, 0), WW - 1);
    int yi0 = min(max(y0 - 1, 0), HH - 1);
    int yi1 = min(max(y1 - 1, 0), HH - 1);

    float wa = dy * dx;                     // (y0, x0)
    float wb = (1.0f - dy) * dx;            // (y1, x0)
    float wc = dy * (1.0f - dx);            // (y0, x1)
    float wd = (1.0f - dy) * (1.0f - dx);   // (y1, x1)

    const _Float16* base = img + (size_t)b * HW * CC + hid * 16;
    const half8* pa = (const half8*)(base + ((size_t)yi0 * WW + xi0) * CC);
    const half8* pb = (const half8*)(base + ((size_t)yi1 * WW + xi0) * CC);
    const half8* pc = (const half8*)(base + ((size_t)yi0 * WW + xi1) * CC);
    const half8* pd = (const half8*)(base + ((size_t)yi1 * WW + xi1) * CC);

    half8 a0 = pa[0], a1 = pa[1];
    half8 b0 = pb[0], b1 = pb[1];
    half8 c0 = pc[0], c1 = pc[1];
    half8 d0 = pd[0], d1 = pd[1];

    float r[16];
    #pragma unroll
    for (int j = 0; j < 8; ++j) {
        r[j]     = wa * (float)a0[j] + wb * (float)b0[j]
                 + wc * (float)c0[j] + wd * (float)d0[j];
        r[j + 8] = wa * (float)a1[j] + wb * (float)b1[j]
                 + wc * (float)c1[j] + wd * (float)d1[j];
    }

    float* outp = out + ((size_t)b * CC + hid * 16) * HW + pixb;
    #pragma unroll
    for (int j = 0; j < 16; ++j) {
        __builtin_nontemporal_store(r[j], outp + j * HW);
    }
}

// ---------------------------------------------------------------------------
// Stage 1: transpose batches 8..15 (TBLK_HALF blocks). Normal img stores:
// leave batch 8..15 images resident in L2 for stage 2's gather.
// ---------------------------------------------------------------------------
__global__ __launch_bounds__(256) void tpass1(
    const float* __restrict__ Im, _Float16* __restrict__ img)
{
    __shared__ float lds[64 * 33];
    int m = blockIdx.x;                // 8192
    int b = 8 + (m & 7);               // XCD-affine: batch b on XCD b-8
    int slot = m >> 3;                 // 0..1023
    transpose_tile(Im, img, b, slot >> 2, (slot & 3) * 64, false, lds);
}

// ---------------------------------------------------------------------------
// Stage 2: gather batches 8..15 overlapped with transpose of batches 0..7.
// 24-block period: [8x gather (one per XCD), 16x transpose (two per XCD)].
// Transpose img writes are NT here so batch 0..7 images don't evict the
// gather's batch 8..15 image (2 x 4 MiB would not fit in 4 MiB XCD-L2).
// ---------------------------------------------------------------------------
__global__ __launch_bounds__(256) void mixpass(
    const float* __restrict__ Im, _Float16* __restrict__ img,
    const float* __restrict__ G, float* __restrict__ out)
{
    __shared__ float lds[64 * 33];
    int m = blockIdx.x;                // MIX_BLOCKS = 12288
    int q = m / 24;                    // 0..511 (period index)
    int r = m - q * 24;                // 0..23 (position in period)
    if (r < 8) {
        gather_unit(img, G, out, 8 + r, q);          // 8 batches x 512 units
    } else {
        int xcd = r & 7;
        int ti  = q * 2 + (r >> 4);                  // 0..1023 per xcd
        transpose_tile(Im, img, xcd, ti >> 2, (ti & 3) * 64, true, lds);
    }
}

// ---------------------------------------------------------------------------
// Stage 3: gather batches 0..7 (GBLK_HALF blocks), images written by stage 2.
// ---------------------------------------------------------------------------
__global__ __launch_bounds__(256) void gpass3(
    const _Float16* __restrict__ img, const float* __restrict__ G,
    float* __restrict__ out)
{
    int m = blockIdx.x;                // 4096
    gather_unit(img, G, out, m & 7, m >> 3);
}

// ---------------------------------------------------------------------------
// Fallback (direct kernel) in case ws is too small.
// ---------------------------------------------------------------------------
__global__ __launch_bounds__(256) void bilerp_direct(
    const float* __restrict__ Im, const float* __restrict__ G,
    float* __restrict__ out)
{
    int idx = blockIdx.x * blockDim.x + threadIdx.x;
    int ox = idx & (OWW - 1);
    int oy = (idx >> 8) & (OHH - 1);
    int b  = idx >> 16;

    const float* Gb = G + (size_t)b * 2 * HW + oy * OWW + ox;
    float x = Gb[0] + 1.0f;
    float y = Gb[HW] + 1.0f;
    int x0 = (int)floorf(x), y0 = (int)floorf(y);
    int x1 = x0 + 1, y1 = y0 + 1;
    x0 = min(max(x0, 0), WW + 1); x1 = min(max(x1, 0), WW + 1);
    y0 = min(max(y0, 0), HH + 1); y1 = min(max(y1, 0), HH + 1);
    float dx = (float)x1 - x, dy = (float)y1 - y;
    int xi0 = min(max(x0 - 1, 0), WW - 1), xi1 = min(max(x1 - 1, 0), WW - 1);
    int yi0 = min(max(y0 - 1, 0), HH - 1), yi1 = min(max(y1 - 1, 0), HH - 1);
    float wa = dy * dx, wb = (1.0f - dy) * dx;
    float wc = dy * (1.0f - dx), wd = (1.0f - dy) * (1.0f - dx);

    const float* Ibase = Im + (size_t)b * CC * HW;
    int o00 = yi0 * WW + xi0, o01 = yi0 * WW + xi1;
    int o10 = yi1 * WW + xi0, o11 = yi1 * WW + xi1;
    float* outp = out + (size_t)b * CC * HW + oy * OWW + ox;
    #pragma unroll 4
    for (int c = 0; c < CC; ++c) {
        const float* p = Ibase + c * HW;
        outp[c * HW] = wa * p[o00] + wb * p[o10] + wc * p[o01] + wd * p[o11];
    }
}

extern "C" void kernel_launch(void* const* d_in, const int* in_sizes, int n_in,
                              void* d_out, int out_size, void* d_ws, size_t ws_size,
                              hipStream_t stream) {
    const float* Im = (const float*)d_in[0];
    const float* G  = (const float*)d_in[1];
    float* out = (float*)d_out;

    const size_t needed = (size_t)BB * HW * CC * sizeof(_Float16);  // 64 MB
    int total = BB * OHH * OWW;

    if (ws_size >= needed) {
        _Float16* nhwc = (_Float16*)d_ws;
        // 3-stage pipeline: T(8..15) ; G(8..15) || T(0..7) ; G(0..7).
        // Kernel boundaries provide the producer->consumer sync — no
        // barriers, no fences, no XCD-coherence assumptions.
        tpass1 <<<dim3(TBLK_HALF),  dim3(256), 0, stream>>>(Im, nhwc);
        mixpass<<<dim3(MIX_BLOCKS), dim3(256), 0, stream>>>(Im, nhwc, G, out);
        gpass3 <<<dim3(GBLK_HALF),  dim3(256), 0, stream>>>(nhwc, G, out);
    } else {
        bilerp_direct<<<dim3(total / 256), dim3(256), 0, stream>>>(Im, G, out);
    }
}